// Round 16
// baseline (2471.804 us; speedup 1.0000x reference)
//
#include <hip/hip_runtime.h>
#include <stdint.h>

// LSTM(relu) persistent kernel v16: B=64,S=1024,F=128,H=512.
// = v15 (best, 2467us: XCD-local groups via HW_REG_XCC_ID, LDS [U;W]^T bf16
// stride 648, 4-wave K-split, per-tile epilogue, per-wg 128B flag lines) with
// the sync protocol refined to PER-WAVE granularity:
//  - producer wave w drains ITS h-store (vmcnt(0)) then stores its OWN flag
//    (line[slot], word w) -> fires at the earliest legal instant (v15's join
//    counter waited for the CU's slowest wave).
//  - consumer wave w polls ONLY its deps: slots 8w..8w+7 x 4 waves = 32 flags
//    (one lane-parallel gather over 8 lines), then starts h@U immediately.
//    Stragglers gate 1/4 of the CU's work, not all of it. barrier1 DELETED.
//  - publish-overwrite safety (v8's silent hole, fixed): publish(t) into
//    buf[(t+1)&1] overwrites the gen consumed at step t-1; it requires all 32
//    flags >= t. Union of the 4 waves' polls(tgt=t) = all 32 slots, and
//    barrier2(t) joins them -> any publish after barrier2(t) is safe.
//  - R single-buffered stays safe: read(t) < barrier2(t) < poll(t+1) <
//    stage-write(t+1) (poll adds ~1.5k cyc separation).
// 256 wgs x 256 thr, ~99KB LDS -> exactly 1 wg/CU (XCD pigeonhole intact).

#define S_ 1024
#define F_ 128
#define H_ 512
#define G4_ 2048
#define KH 16           // h@U K-steps (512/32)
#define KDIM 640
#define LDKS 648        // padded LDS stride (shorts)
#define HB (64 * H_)    // one h buffer: 64 rows x 512 units (bf16)
#define FLW 32          // uints per flag line (128B)

typedef __attribute__((ext_vector_type(8))) short short8;  // 8 x bf16
typedef __attribute__((ext_vector_type(4))) float f32x4;
typedef unsigned long long ull;

__device__ __forceinline__ unsigned short f2bf(float f) {
  union { float f; unsigned u; } v; v.f = f;
  unsigned u = v.u + 0x7fffu + ((v.u >> 16) & 1u);   // RNE
  return (unsigned short)(u >> 16);
}

__device__ __forceinline__ short8 pack2(f32x4 a, f32x4 b) {
  short8 r;
#pragma unroll
  for (int i = 0; i < 4; ++i) r[i] = (short)f2bf(a[i]);
#pragma unroll
  for (int i = 0; i < 4; ++i) r[4 + i] = (short)f2bf(b[i]);
  return r;
}

__global__ __launch_bounds__(256, 1) void lstm_pers(
    const float* __restrict__ x, const float* __restrict__ W,
    const float* __restrict__ U, const float* __restrict__ bias,
    float* __restrict__ out, unsigned int* ws_sync, unsigned short* hbuf) {

  __shared__ unsigned short V[64 * LDKS];   // 82944 B
  __shared__ f32x4 R[4][4][64];             // 16384 B partial staging
  __shared__ int meta[2];

  const int tid  = threadIdx.x;
  const int w    = tid >> 6;           // wave 0..3 (k-steps 4w..4w+3; tile w)
  const int lane = tid & 63;
  const int l15  = lane & 15;
  const int l4   = lane >> 4;
  const int koff = l4 * 8;

  // ---- physical XCD id + slot claim (robust group formation) ----
  if (tid == 0) {
    unsigned int xcc;
    asm volatile("s_getreg_b32 %0, hwreg(20, 0, 4)" : "=s"(xcc));  // HW_REG_XCC_ID
    xcc &= 7;
    unsigned sv = atomicAdd(ws_sync + xcc * 32, 1u);   // 128B-spaced ctrs
    meta[0] = (int)xcc;
    meta[1] = (int)(sv & 31);
  }
  __syncthreads();
  const int xcc  = meta[0];
  const int slot = meta[1];

  // flags: ONE 128B LINE PER WG; words 0..3 = waves 0..3
  unsigned int* gflags = ws_sync + 256 + xcc * (32 * FLW);
  unsigned int* myflag = gflags + slot * FLW + w;
  // consumer wave w's dep flags: slots 8w..8w+7, all 4 waves (32 flags).
  // lane i (dup for i>=32): wg slot 8w + ((i&31)>>2), wave (i&3).
  unsigned int* pollp  = gflags + (8 * w + ((lane & 31) >> 2)) * FLW + (lane & 3);

  const int u0    = slot * 16;       // 16 units per wg
  const int bbase = xcc * 8;         // 8 batch rows per group

  // ---- LDS fill (validated decomposition, stride 648) ----
  for (int idx = tid; idx < (64 * KDIM) / 4; idx += 256) {
    const int q4   = idx & 15;
    const int k    = idx >> 4;                // 0..639
    const int gate = q4 & 3;
    const int ul0  = (q4 >> 2) * 4;           // 0,4,8,12
    const int col  = gate * H_ + u0 + ul0;
    const float* src = (k < H_) ? (U + (size_t)k * G4_ + col)
                                : (W + (size_t)(k - H_) * G4_ + col);
    const f32x4 v4 = *(const f32x4*)src;
#pragma unroll
    for (int q = 0; q < 4; ++q) {
      const int ul = ul0 + q;
      const int cc = (ul >> 2) * 16 + (ul & 3) * 4 + gate;
      V[cc * LDKS + k] = f2bf(v4[q]);
    }
  }

  // wave w's gate bias for tile w: unit = u0 + w*4 + l4
  float bias_r[4];
#pragma unroll
  for (int g = 0; g < 4; ++g) bias_r[g] = bias[g * H_ + u0 + w * 4 + l4];

  __syncthreads();

  const int brow = bbase + (l15 & 7);   // rows duplicated for l15>=8
  const float* xrow = x + (size_t)brow * S_ * F_ + koff + w * 32;
  const unsigned short* hrow0 = hbuf + (size_t)brow * H_ + koff;
  const int myunit = u0 + w * 4 + l4;   // this lane's (row,unit) in tile w

  float cst = 0.f;                      // c-state of (brow, myunit)

  // preload x(0) slice for this wave
  f32x4 xa = *(const f32x4*)(xrow);
  f32x4 xb = *(const f32x4*)(xrow + 4);

  for (int t = 0; t < S_; ++t) {
    // ---- x @ W first (h-independent): hides poll latency below ----
    f32x4 acc[4];
#pragma unroll
    for (int tl = 0; tl < 4; ++tl) { acc[tl][0]=0.f; acc[tl][1]=0.f; acc[tl][2]=0.f; acc[tl][3]=0.f; }
    {
      const short8 bx = pack2(xa, xb);
      const int k0 = (KH + w) * 32 + koff;
#pragma unroll
      for (int tl = 0; tl < 4; ++tl) {
        const short8 a = *(const short8*)&V[(tl * 16 + l15) * LDKS + k0];
        acc[tl] = __builtin_amdgcn_mfma_f32_16x16x32_bf16(a, bx, acc[tl], 0, 0, 0);
      }
    }

    // ---- issue x(t+1) loads now; they complete under h@U ----
    {
      const int tn = (t + 1 < S_) ? t + 1 : t;
      const float* xt = xrow + (size_t)tn * F_;
      xa = *(const f32x4*)(xt);
      xb = *(const f32x4*)(xt + 4);
    }

    // ---- EACH wave polls its own 32 dep flags; start h@U on arrival ----
    if (t > 0) {
      const unsigned tgt = (unsigned)t;
      while (true) {
        const unsigned v = __hip_atomic_load(pollp, __ATOMIC_RELAXED, __HIP_MEMORY_SCOPE_AGENT);
        if (__all((int)(v >= tgt))) break;
      }

      // ---- my 4 h B-frags (k-steps 4w..4w+3) + h@U ----
      const unsigned short* hr = hrow0 + (size_t)(t & 1) * HB;
      short8 bh[4];
#pragma unroll
      for (int i = 0; i < 4; ++i) {
        union { ull u[2]; short8 s; } bb;
        const ull* hq = (const ull*)(hr + (4 * w + i) * 32);
        bb.u[0] = __hip_atomic_load(hq,     __ATOMIC_RELAXED, __HIP_MEMORY_SCOPE_AGENT);
        bb.u[1] = __hip_atomic_load(hq + 1, __ATOMIC_RELAXED, __HIP_MEMORY_SCOPE_AGENT);
        bh[i] = bb.s;
      }
#pragma unroll
      for (int i = 0; i < 4; ++i) {
        const int k0 = (4 * w + i) * 32 + koff;
#pragma unroll
        for (int tl = 0; tl < 4; ++tl) {
          const short8 a = *(const short8*)&V[(tl * 16 + l15) * LDKS + k0];
          acc[tl] = __builtin_amdgcn_mfma_f32_16x16x32_bf16(a, bh[i], acc[tl], 0, 0, 0);
        }
      }
    }

    // ---- stage partials; barrier2 (sole barrier: reduce sync + publish gate:
    //      union of the 4 waves' polls(tgt=t) = all 32 slots >= t) ----
#pragma unroll
    for (int tl = 0; tl < 4; ++tl) R[w][tl][lane] = acc[tl];
    __syncthreads();
    // single-buffered R safe: read(t) < barrier2(t) < poll(t+1) < write(t+1).

    f32x4 z;
    {
      const f32x4 r0 = R[0][w][lane], r1 = R[1][w][lane],
                  r2 = R[2][w][lane], r3 = R[3][w][lane];
#pragma unroll
      for (int g = 0; g < 4; ++g)
        z[g] = bias_r[g] + r0[g] + r1[g] + r2[g] + r3[g];
    }

    // ---- gates for (brow, myunit) ----
    const float ig = 1.f / (1.f + __expf(-z[0]));
    const float fg = 1.f / (1.f + __expf(-z[1]));
    const float gg = fmaxf(z[2], 0.f);             // relu candidate
    const float og = 1.f / (1.f + __expf(-z[3]));
    const float cn = fg * cst + ig * gg;
    cst = cn;
    const float hv = og * fmaxf(cn, 0.f);          // relu output activation

    // ---- publish: h store; drain MY stores; store MY wave flag ----
    if (l15 < 8)
      hbuf[(size_t)((t + 1) & 1) * HB + (size_t)brow * H_ + myunit] = f2bf(hv);
    asm volatile("s_waitcnt vmcnt(0)" ::: "memory");   // my h slice acked

    if (lane == 0)
      __hip_atomic_store(myflag, (unsigned)(t + 1),
                         __ATOMIC_RELAXED, __HIP_MEMORY_SCOPE_AGENT);

    if (l15 < 8)
      out[((size_t)brow * S_ + t) * H_ + myunit] = hv;   // off the publish path
  }
}

extern "C" void kernel_launch(void* const* d_in, const int* in_sizes, int n_in,
                              void* d_out, int out_size, void* d_ws, size_t ws_size,
                              hipStream_t stream) {
  const float* x = (const float*)d_in[0];
  const float* W = (const float*)d_in[1];
  const float* U = (const float*)d_in[2];
  const float* b = (const float*)d_in[3];
  float* out = (float*)d_out;

  unsigned int*   ws_sync = (unsigned int*)d_ws;                    // ctrs(1KB) + flag lines(32KB)
  unsigned short* hbuf    = (unsigned short*)((char*)d_ws + 65536); // 2 x 64 x 512 bf16 = 128KB

  hipMemsetAsync(d_ws, 0, 65536, stream);   // zero slot ctrs + all flag lines

  lstm_pers<<<dim3(256), dim3(256), 0, stream>>>(x, W, U, b, out, ws_sync, hbuf);
}

// Round 17
// 2458.511 us; speedup vs baseline: 1.0054x; 1.0054x over previous
//
#include <hip/hip_runtime.h>
#include <stdint.h>

// LSTM(relu) persistent kernel v17: B=64,S=1024,F=128,H=512.
// = v16 skeleton (XCD-local groups via HW_REG_XCC_ID, LDS [U;W]^T bf16 stride
// 648, 4-wave K-split, per-tile epilogue, single barrier + R staging) with the
// flag protocol replaced by SINGLE-HOP TAGGED-DATA sync (v13 semantics, v14's
// coalesced publish, neither's mistakes):
//  - h >= 0 (sigmoid*relu) -> bf16 sign bit is free. Producer wave w gathers
//    each row's 4 units via 3 shuffles and stores ONE u64 per row, all 4
//    halfword signs = marker(t) = ((t>>1)&1)^1. No vmcnt drain, no flags.
//  - Consumer wave w spins directly on the 8 u64s it needs (64B/lane/iter,
//    v13-proven bandwidth): the poll IS the data. One memory RT on the
//    critical path instead of flag-propagate + poll + separate load.
//  - No epoch gate needed: wave w's poll covers slots 8w..8w+7; union over
//    4 waves = all 32 slots; publish is after barrier2 -> publish(t) proves
//    all wgs finished reading gen t-2 (the buffer being overwritten).
//    Marker alternates every 2 steps -> distinguishes gen t-1 / t-3 / init-0.
// 256 wgs x 256 thr, ~99KB LDS -> exactly 1 wg/CU (XCD pigeonhole intact).

#define S_ 1024
#define F_ 128
#define H_ 512
#define G4_ 2048
#define KH 16           // h@U K-steps (512/32)
#define KDIM 640
#define LDKS 648        // padded LDS stride (shorts)
#define HB (64 * H_)    // one h buffer: 64 rows x 512 units (bf16, sign=marker)
#define SMASK8 0x8000800080008000ull
#define VMASK8 0x7FFF7FFF7FFF7FFFull

typedef __attribute__((ext_vector_type(8))) short short8;  // 8 x bf16
typedef __attribute__((ext_vector_type(4))) float f32x4;
typedef unsigned long long ull;

__device__ __forceinline__ unsigned short f2bf(float f) {
  union { float f; unsigned u; } v; v.f = f;
  unsigned u = v.u + 0x7fffu + ((v.u >> 16) & 1u);   // RNE
  return (unsigned short)(u >> 16);
}

__device__ __forceinline__ short8 pack2(f32x4 a, f32x4 b) {
  short8 r;
#pragma unroll
  for (int i = 0; i < 4; ++i) r[i] = (short)f2bf(a[i]);
#pragma unroll
  for (int i = 0; i < 4; ++i) r[4 + i] = (short)f2bf(b[i]);
  return r;
}

__global__ __launch_bounds__(256, 1) void lstm_pers(
    const float* __restrict__ x, const float* __restrict__ W,
    const float* __restrict__ U, const float* __restrict__ bias,
    float* __restrict__ out, unsigned int* ws_sync, unsigned short* hbuf) {

  __shared__ unsigned short V[64 * LDKS];   // 82944 B
  __shared__ f32x4 R[4][4][64];             // 16384 B partial staging
  __shared__ int meta[2];

  const int tid  = threadIdx.x;
  const int w    = tid >> 6;           // wave 0..3 (k-steps 4w..4w+3; tile w)
  const int lane = tid & 63;
  const int l15  = lane & 15;
  const int l4   = lane >> 4;
  const int koff = l4 * 8;

  // ---- physical XCD id + slot claim (robust group formation) ----
  if (tid == 0) {
    unsigned int xcc;
    asm volatile("s_getreg_b32 %0, hwreg(20, 0, 4)" : "=s"(xcc));  // HW_REG_XCC_ID
    xcc &= 7;
    unsigned sv = atomicAdd(ws_sync + xcc * 32, 1u);   // 128B-spaced ctrs
    meta[0] = (int)xcc;
    meta[1] = (int)(sv & 31);
  }
  __syncthreads();
  const int xcc  = meta[0];
  const int slot = meta[1];

  const int u0    = slot * 16;       // 16 units per wg
  const int bbase = xcc * 8;         // 8 batch rows per group

  // ---- LDS fill (validated decomposition, stride 648) ----
  for (int idx = tid; idx < (64 * KDIM) / 4; idx += 256) {
    const int q4   = idx & 15;
    const int k    = idx >> 4;                // 0..639
    const int gate = q4 & 3;
    const int ul0  = (q4 >> 2) * 4;           // 0,4,8,12
    const int col  = gate * H_ + u0 + ul0;
    const float* src = (k < H_) ? (U + (size_t)k * G4_ + col)
                                : (W + (size_t)(k - H_) * G4_ + col);
    const f32x4 v4 = *(const f32x4*)src;
#pragma unroll
    for (int q = 0; q < 4; ++q) {
      const int ul = ul0 + q;
      const int cc = (ul >> 2) * 16 + (ul & 3) * 4 + gate;
      V[cc * LDKS + k] = f2bf(v4[q]);
    }
  }

  // wave w's gate bias for tile w: unit = u0 + w*4 + l4
  float bias_r[4];
#pragma unroll
  for (int g = 0; g < 4; ++g) bias_r[g] = bias[g * H_ + u0 + w * 4 + l4];

  __syncthreads();

  const int brow = bbase + (l15 & 7);   // rows duplicated for l15>=8
  const float* xrow = x + (size_t)brow * S_ * F_ + koff + w * 32;
  const unsigned short* hrow0 = hbuf + (size_t)brow * H_ + koff;
  const int myunit = u0 + w * 4 + l4;   // this lane's (row,unit) in tile w

  float cst = 0.f;                      // c-state of (brow, myunit)

  // preload x(0) slice for this wave
  f32x4 xa = *(const f32x4*)(xrow);
  f32x4 xb = *(const f32x4*)(xrow + 4);

  for (int t = 0; t < S_; ++t) {
    // ---- x @ W first (h-independent): hides the data-poll below ----
    f32x4 acc[4];
#pragma unroll
    for (int tl = 0; tl < 4; ++tl) { acc[tl][0]=0.f; acc[tl][1]=0.f; acc[tl][2]=0.f; acc[tl][3]=0.f; }
    {
      const short8 bx = pack2(xa, xb);
      const int k0 = (KH + w) * 32 + koff;
#pragma unroll
      for (int tl = 0; tl < 4; ++tl) {
        const short8 a = *(const short8*)&V[(tl * 16 + l15) * LDKS + k0];
        acc[tl] = __builtin_amdgcn_mfma_f32_16x16x32_bf16(a, bx, acc[tl], 0, 0, 0);
      }
    }

    // ---- issue x(t+1) loads now; they complete under h@U ----
    {
      const int tn = (t + 1 < S_) ? t + 1 : t;
      const float* xt = xrow + (size_t)tn * F_;
      xa = *(const f32x4*)(xt);
      xb = *(const f32x4*)(xt + 4);
    }

    // ---- tagged data-poll of MY 4 h k-steps: poll IS the data ----
    if (t > 0) {
      const ull expm = (((((unsigned)(t - 1)) >> 1) & 1u) ^ 1u) ? SMASK8 : 0ull;
      const unsigned short* hr = hrow0 + (size_t)(t & 1) * HB;
      const ull* q0 = (const ull*)(hr + (4 * w + 0) * 32);
      const ull* q1 = (const ull*)(hr + (4 * w + 1) * 32);
      const ull* q2 = (const ull*)(hr + (4 * w + 2) * 32);
      const ull* q3 = (const ull*)(hr + (4 * w + 3) * 32);
      ull d0, d1, d2, d3, d4, d5, d6, d7;
      while (true) {
        d0 = __hip_atomic_load(q0,     __ATOMIC_RELAXED, __HIP_MEMORY_SCOPE_AGENT);
        d1 = __hip_atomic_load(q0 + 1, __ATOMIC_RELAXED, __HIP_MEMORY_SCOPE_AGENT);
        d2 = __hip_atomic_load(q1,     __ATOMIC_RELAXED, __HIP_MEMORY_SCOPE_AGENT);
        d3 = __hip_atomic_load(q1 + 1, __ATOMIC_RELAXED, __HIP_MEMORY_SCOPE_AGENT);
        d4 = __hip_atomic_load(q2,     __ATOMIC_RELAXED, __HIP_MEMORY_SCOPE_AGENT);
        d5 = __hip_atomic_load(q2 + 1, __ATOMIC_RELAXED, __HIP_MEMORY_SCOPE_AGENT);
        d6 = __hip_atomic_load(q3,     __ATOMIC_RELAXED, __HIP_MEMORY_SCOPE_AGENT);
        d7 = __hip_atomic_load(q3 + 1, __ATOMIC_RELAXED, __HIP_MEMORY_SCOPE_AGENT);
        const ull bad = (d0 ^ expm) | (d1 ^ expm) | (d2 ^ expm) | (d3 ^ expm) |
                        (d4 ^ expm) | (d5 ^ expm) | (d6 ^ expm) | (d7 ^ expm);
        if (__all((int)((bad & SMASK8) == 0ull))) break;
      }
      // strip markers -> B-frags -> h@U MFMAs
      union { ull u[2]; short8 s; } b0, b1, b2, b3;
      b0.u[0] = d0 & VMASK8; b0.u[1] = d1 & VMASK8;
      b1.u[0] = d2 & VMASK8; b1.u[1] = d3 & VMASK8;
      b2.u[0] = d4 & VMASK8; b2.u[1] = d5 & VMASK8;
      b3.u[0] = d6 & VMASK8; b3.u[1] = d7 & VMASK8;
      const short8 bh[4] = {b0.s, b1.s, b2.s, b3.s};
#pragma unroll
      for (int i = 0; i < 4; ++i) {
        const int k0 = (4 * w + i) * 32 + koff;
#pragma unroll
        for (int tl = 0; tl < 4; ++tl) {
          const short8 a = *(const short8*)&V[(tl * 16 + l15) * LDKS + k0];
          acc[tl] = __builtin_amdgcn_mfma_f32_16x16x32_bf16(a, bh[i], acc[tl], 0, 0, 0);
        }
      }
    }

    // ---- stage partials; barrier2 (reduce sync + publish gate: union of
    //      the 4 waves' data-polls = all 32 slots at gen t-1) ----
#pragma unroll
    for (int tl = 0; tl < 4; ++tl) R[w][tl][lane] = acc[tl];
    __syncthreads();
    // single-buffered R safe: read(t) < barrier2(t) < poll(t+1) < write(t+1).

    f32x4 z;
    {
      const f32x4 r0 = R[0][w][lane], r1 = R[1][w][lane],
                  r2 = R[2][w][lane], r3 = R[3][w][lane];
#pragma unroll
      for (int g = 0; g < 4; ++g)
        z[g] = bias_r[g] + r0[g] + r1[g] + r2[g] + r3[g];
    }

    // ---- gates for (brow, myunit) ----
    const float ig = 1.f / (1.f + __expf(-z[0]));
    const float fg = 1.f / (1.f + __expf(-z[1]));
    const float gg = fmaxf(z[2], 0.f);             // relu candidate
    const float og = 1.f / (1.f + __expf(-z[3]));
    const float cn = fg * cst + ig * gg;
    cst = cn;
    const float hv = og * fmaxf(cn, 0.f);          // relu output (>= 0)

    // ---- gather row's 4 units -> ONE tagged u64 per row; store = sync ----
    const unsigned hb0 = (unsigned)f2bf(hv);
    const unsigned hb1 = (unsigned)__shfl((int)hb0, (lane & 7) + 16);
    const unsigned hb2 = (unsigned)__shfl((int)hb0, (lane & 7) + 32);
    const unsigned hb3 = (unsigned)__shfl((int)hb0, (lane & 7) + 48);
    const ull tagw = ((((unsigned)t >> 1) & 1u) ^ 1u) ? SMASK8 : 0ull;
    const ull wrd = (ull)(hb0 & 0xFFFFu) | ((ull)(hb1 & 0xFFFFu) << 16) |
                    ((ull)(hb2 & 0xFFFFu) << 32) | ((ull)(hb3 & 0xFFFFu) << 48) | tagw;
    if (lane < 8) {
      ull* dst = (ull*)(hbuf + (size_t)((t + 1) & 1) * HB +
                        (size_t)(bbase + lane) * H_ + u0 + w * 4);
      __hip_atomic_store(dst, wrd, __ATOMIC_RELAXED, __HIP_MEMORY_SCOPE_AGENT);
    }

    if (l15 < 8)
      out[((size_t)brow * S_ + t) * H_ + myunit] = hv;   // off the publish path
  }
}

extern "C" void kernel_launch(void* const* d_in, const int* in_sizes, int n_in,
                              void* d_out, int out_size, void* d_ws, size_t ws_size,
                              hipStream_t stream) {
  const float* x = (const float*)d_in[0];
  const float* W = (const float*)d_in[1];
  const float* U = (const float*)d_in[2];
  const float* b = (const float*)d_in[3];
  float* out = (float*)d_out;

  unsigned int*   ws_sync = (unsigned int*)d_ws;                   // slot ctrs (1KB)
  unsigned short* hbuf    = (unsigned short*)((char*)d_ws + 1024); // 2 x 64 x 512 bf16 = 128KB

  // zero ctrs + BOTH tagged h buffers (markers must start invalid = 0)
  hipMemsetAsync(d_ws, 0, 1024 + 2 * HB * sizeof(unsigned short), stream);

  lstm_pers<<<dim3(256), dim3(256), 0, stream>>>(x, W, U, b, out, ws_sync, hbuf);
}